// Round 5
// baseline (866.150 us; speedup 1.0000x reference)
//
#include <hip/hip_runtime.h>
#include <hip/hip_bf16.h>

// ---------------------------------------------------------------------------
// WeightOnlyLinear: y = x @ dequant4(qweight, scales, qzeros) + bias
//   x (8192,4096) fp32 | scales (32,12288) | bias (12288) | qweight (512,12288)
//   qzeros (32,1536) | out (8192,12288) fp32
// R5: ring-of-4 K-half slots + REGISTER PING-PONG fragments: phase q's MFMAs
//     run from registers read during phase q-1; this phase's ds_reads (next
//     frags + mh1 half) and stage loads overlap under the MFMA clusters.
//     1 barrier + 1 counted vmcnt per 32-MFMA phase. T1 + T5 retained.
// ---------------------------------------------------------------------------

typedef __attribute__((ext_vector_type(8))) short short8;
typedef __attribute__((ext_vector_type(4))) float f32x4;

__device__ __forceinline__ short f2bf(float f) {
  unsigned u = __float_as_uint(f);
  u += 0x7fffu + ((u >> 16) & 1u);
  return (short)(u >> 16);
}

__device__ __forceinline__ void gload_lds16(const void* g, void* l) {
  __builtin_amdgcn_global_load_lds(
      (const __attribute__((address_space(1))) void*)g,
      (__attribute__((address_space(3))) void*)l,
      16, 0, 0);
}

__device__ __forceinline__ void bar() {
  asm volatile("" ::: "memory");
  __builtin_amdgcn_s_barrier();
  asm volatile("" ::: "memory");
}
__device__ __forceinline__ void wait_vm4() {
  asm volatile("s_waitcnt vmcnt(4)" ::: "memory");
}
__device__ __forceinline__ void wait_vm0() {
  asm volatile("s_waitcnt vmcnt(0)" ::: "memory");
}

// ---------------------------------------------------------------------------
// Pass 1: dequant + transpose. qweight (K/8, N) int32 -> Wt (N, K) bf16.
// ---------------------------------------------------------------------------
__global__ __launch_bounds__(256) void dequant_kernel(
    const int* __restrict__ qweight, const int* __restrict__ qzeros,
    const float* __restrict__ scales, short* __restrict__ Wt,
    int in_f, int out_f) {
  __shared__ __align__(16) short T[64][72];
  const int n0 = blockIdx.x * 64;
  const int k0 = blockIdx.y * 64;
  const int t = threadIdx.x;
  const int nl = t & 63;
  const int kw = t >> 6;
  const int n = n0 + nl;
  const int g = k0 >> 7;
  const float sc = scales[(size_t)g * out_f + n];
  const int zpw = qzeros[(size_t)g * (out_f >> 3) + (n >> 3)];
  const float zp = (float)(((zpw >> ((n & 7) * 4)) & 15) + 1);
  const float zs = zp * sc;
#pragma unroll
  for (int rr = 0; rr < 2; ++rr) {
    const int kwi = kw + rr * 4;
    const int w = qweight[(size_t)((k0 >> 3) + kwi) * out_f + n];
    short8 v;
#pragma unroll
    for (int e = 0; e < 8; ++e) {
      float f = (float)((w >> (4 * e)) & 15) * sc - zs;
      v[e] = f2bf(f);
    }
    *(short8*)&T[nl][kwi * 8] = v;
  }
  __syncthreads();
#pragma unroll
  for (int rr = 0; rr < 2; ++rr) {
    const int c = rr * 256 + t;
    const int row = c >> 3, ch = c & 7;
    *(short8*)&Wt[(size_t)(n0 + row) * in_f + k0 + ch * 8] =
        *(const short8*)&T[row][ch * 8];
  }
}

// ---------------------------------------------------------------------------
// Pass 2: x fp32 -> bf16.
// ---------------------------------------------------------------------------
__global__ __launch_bounds__(256) void cvt_kernel(
    const float* __restrict__ x, short* __restrict__ xb, long n8) {
  long i = (long)blockIdx.x * blockDim.x + threadIdx.x;
  if (i >= n8) return;
  const float* src = x + i * 8;
  float4 a = *(const float4*)src;
  float4 b = *(const float4*)(src + 4);
  short8 v;
  v[0] = f2bf(a.x); v[1] = f2bf(a.y); v[2] = f2bf(a.z); v[3] = f2bf(a.w);
  v[4] = f2bf(b.x); v[5] = f2bf(b.y); v[6] = f2bf(b.z); v[7] = f2bf(b.w);
  *(short8*)(xb + i * 8) = v;
}

// ---------------------------------------------------------------------------
// Pass 3 (R5): 256x256 GEMM, 512 threads = 8 waves (2M x 4N).
// LDS ring: 4 slots x 32KB (K-half h: A[256][32] @0, B[256][32] @16384).
// Chunk (row,q) at byte row*64 + (q ^ ((row>>1)&3))*16 (0-conflict verified).
//
// Body q (steady state):
//   [regs hold frags for phase q: afC (mh0 rows), bfC]
//   4x ds_read  af2   <- slot q      (mh1 rows; oldest lgkm group)
//   8x ds_read  nxt   <- slot q+1    (frags for phase q+1)
//   4x gload    stage -> slot (q+3)&3   [== (q-1)&3, reads retired @bar q-1]
//   16 MFMA mh0 (afC,bfC)            [NO lgkm dependence -> issues at once]
//   16 MFMA mh1 (af2,bfC)            [auto lgkmcnt(8): waits af2 only]
//   vmcnt(4) [slot q+2 landed] ; s_barrier
// Prologue: stage slots 0,1,2; vmcnt(4) [slots 0 AND 1 landed]; bar;
//           read frags(phase 0) from slot 0.
// Tail: body P-3 -> vmcnt(0)+bar (slot P-1 confirmed); P-2, P-1 -> no sync.
// ---------------------------------------------------------------------------
#define GBM 256
#define GBN 256

__global__ __launch_bounds__(512, 2) void gemm256_kernel(
    const short* __restrict__ A, const short* __restrict__ Bt,
    const float* __restrict__ bias, float* __restrict__ C,
    int M, int N, int K) {
  __shared__ __align__(16) char lds[4][32768];
  const int tid = threadIdx.x;
  const int nbx = N / GBN;
  const int nwg = gridDim.x;
  int bid = blockIdx.x;
  if ((nwg & 7) == 0) bid = (bid & 7) * (nwg >> 3) + (bid >> 3);  // T1
  const int bm = (bid / nbx) * GBM;
  const int bn = (bid % nbx) * GBN;

  const int wid = tid >> 6, lane = tid & 63;
  const int wr = wid >> 2, wc = wid & 3;  // 2x4 wave grid
  const int lrow = lane & 15;
  const int lq = lane >> 4;  // k-quarter within the 32-k half

  const int P = K >> 5;  // phases; P % 4 == 0, P >= 4 (K % 128 == 0)

  // --- ds_read base addresses; i/j offsets are compile-time immediates
  // (16-row steps shift row>>1 by 8 -> (row>>1)&3 invariant across i,mh,j)
  const int rowA = wr * 128 + lrow;
  const int sA = lq ^ ((rowA >> 1) & 3);
  const int baseA = rowA * 64 + sA * 16;
  const int rowB = wc * 64 + lrow;
  const int sB = lq ^ ((rowB >> 1) & 3);
  const int baseB = 16384 + rowB * 64 + sB * 16;

  // --- stage addressing: chunks c = tid, tid+512 (inverse permutation) ---
  const int c0 = tid, c1 = tid + 512;
  const int rA0 = c0 >> 2, qA0 = (c0 & 3) ^ ((rA0 >> 1) & 3);
  const int rA1 = c1 >> 2, qA1 = (c1 & 3) ^ ((rA1 >> 1) & 3);
  const short* srcA0 = A + (size_t)(bm + rA0) * K + qA0 * 8;
  const short* srcA1 = A + (size_t)(bm + rA1) * K + qA1 * 8;
  const short* srcB0 = Bt + (size_t)(bn + rA0) * K + qA0 * 8;
  const short* srcB1 = Bt + (size_t)(bn + rA1) * K + qA1 * 8;
  const int dA0 = c0 * 16, dA1 = c1 * 16;
  const int dB0 = 16384 + c0 * 16, dB1 = 16384 + c1 * 16;

  auto STAGE = [&](int slot, int h) {
    const int kof = h * 32;
    char* sb = &lds[slot][0];
    gload_lds16(srcA0 + kof, sb + dA0);
    gload_lds16(srcA1 + kof, sb + dA1);
    gload_lds16(srcB0 + kof, sb + dB0);
    gload_lds16(srcB1 + kof, sb + dB1);
  };

  f32x4 acc[8][4] = {};

  auto rdB4 = [&](const char* sb, short8(&bf)[4]) {
#pragma unroll
    for (int j = 0; j < 4; ++j)
      bf[j] = *(const short8*)(sb + baseB + j * 1024);
  };
  auto rdA_mh0 = [&](const char* sb, short8(&af)[4]) {
#pragma unroll
    for (int i = 0; i < 4; ++i)
      af[i] = *(const short8*)(sb + baseA + i * 1024);
  };
  auto rdA_mh1 = [&](const char* sb, short8(&af)[4]) {
#pragma unroll
    for (int i = 0; i < 4; ++i)
      af[i] = *(const short8*)(sb + baseA + 4096 + i * 1024);
  };

  auto BODY = [&](int q, short8(&afC)[4], short8(&bfC)[4], short8(&afN)[4],
                  short8(&bfN)[4]) {
    const char* sbC = &lds[q & 3][0];
    short8 af2[4];
    rdA_mh1(sbC, af2);  // oldest 4 lgkm ops -> mh1 waits lgkmcnt(8)
    if (q + 1 < P) {
      const char* sbN = &lds[(q + 1) & 3][0];
      rdB4(sbN, bfN);
      rdA_mh0(sbN, afN);
    }
    if (q + 3 < P) STAGE((q + 3) & 3, q + 3);
    __builtin_amdgcn_s_setprio(1);
#pragma unroll
    for (int i = 0; i < 4; ++i)
#pragma unroll
      for (int j = 0; j < 4; ++j)
        acc[i][j] = __builtin_amdgcn_mfma_f32_16x16x32_bf16(
            afC[i], bfC[j], acc[i][j], 0, 0, 0);
    __builtin_amdgcn_s_setprio(0);
    __builtin_amdgcn_s_setprio(1);
#pragma unroll
    for (int i = 0; i < 4; ++i)
#pragma unroll
      for (int j = 0; j < 4; ++j)
        acc[4 + i][j] = __builtin_amdgcn_mfma_f32_16x16x32_bf16(
            af2[i], bfC[j], acc[4 + i][j], 0, 0, 0);
    __builtin_amdgcn_s_setprio(0);
    if (q <= P - 4) {
      wait_vm4();  // slot q+2 (issued body q-1) landed; slot q+3 in flight
      bar();
    } else if (q == P - 3) {
      wait_vm0();  // slot P-1 landed (read by body P-2's nxt loads)
      bar();
    }  // bodies P-2, P-1: no further sync needed
  };

  // ping-pong fragment buffers (all statically indexed)
  short8 afA[4], bfA[4], afB[4], bfB[4];

  // --- prologue: stage K-halves 0,1,2; confirm 0 AND 1; read phase-0 frags
  STAGE(0, 0);
  STAGE(1, 1);
  STAGE(2, 2);
  wait_vm4();  // slots 0,1 landed (slot 2 still in flight)
  bar();
  rdB4(&lds[0][0], bfA);
  rdA_mh0(&lds[0][0], afA);

  for (int p = 0; p < P; p += 2) {
    BODY(p, afA, bfA, afB, bfB);
    BODY(p + 1, afB, bfB, afA, bfA);
  }

  // --- epilogue: C = acc + bias. C/D map: col=lane&15, row=(lane>>4)*4+reg
  const int crow0 = bm + wr * 128 + (lane >> 4) * 4;
  const int ccol0 = bn + wc * 64 + (lane & 15);
#pragma unroll
  for (int j = 0; j < 4; ++j) {
    const float bv = bias[ccol0 + j * 16];
#pragma unroll
    for (int i = 0; i < 8; ++i) {
#pragma unroll
      for (int r = 0; r < 4; ++r) {
        C[(size_t)(crow0 + i * 16 + r) * N + ccol0 + j * 16] =
            acc[i][j][r] + bv;
      }
    }
  }
}

// ---------------------------------------------------------------------------
// 128x128x64 GEMM (fallback for non-256-divisible shapes).
// ---------------------------------------------------------------------------
#define BM 128
#define BN 128
#define BK 64

template <bool A_BF16>
__global__ __launch_bounds__(256) void gemm_bias_kernel(
    const void* __restrict__ Av, const short* __restrict__ Bt,
    const float* __restrict__ bias, float* __restrict__ C,
    int M, int N, int K) {
  __shared__ __align__(16) short As[BM * BK];
  __shared__ __align__(16) short Bs[BN * BK];
  const int tid = threadIdx.x;
  const int bm = blockIdx.y * BM;
  const int bn = blockIdx.x * BN;
  const int wid = tid >> 6, lane = tid & 63;
  const int wr = wid >> 1, wc = wid & 1;
  const int lrow = lane & 15;
  const int lk = (lane >> 4) * 8;

  f32x4 acc[4][4] = {};

  for (int kt = 0; kt < K; kt += BK) {
    if constexpr (A_BF16) {
      const short* A = (const short*)Av;
#pragma unroll
      for (int r = 0; r < 4; ++r) {
        const int c = r * 256 + tid;
        const int row = c >> 3, ch = c & 7;
        gload_lds16(A + (size_t)(bm + row) * K + kt + ch * 8,
                    (char*)As + c * 16);
      }
    } else {
      const float* A = (const float*)Av;
#pragma unroll
      for (int r = 0; r < 4; ++r) {
        const int c = r * 256 + tid;
        const int row = c >> 3, ch = c & 7;
        const float* src = A + (size_t)(bm + row) * K + kt + ch * 8;
        float4 f0 = *(const float4*)src;
        float4 f1 = *(const float4*)(src + 4);
        short8 v;
        v[0] = f2bf(f0.x); v[1] = f2bf(f0.y); v[2] = f2bf(f0.z); v[3] = f2bf(f0.w);
        v[4] = f2bf(f1.x); v[5] = f2bf(f1.y); v[6] = f2bf(f1.z); v[7] = f2bf(f1.w);
        *(short8*)((char*)As + c * 16) = v;
      }
    }
#pragma unroll
    for (int r = 0; r < 4; ++r) {
      const int c = r * 256 + tid;
      const int row = c >> 3, ch = c & 7;
      gload_lds16(Bt + (size_t)(bn + row) * K + kt + ch * 8,
                  (char*)Bs + c * 16);
    }
    __syncthreads();
#pragma unroll
    for (int kk = 0; kk < 2; ++kk) {
      short8 af[4], bf[4];
#pragma unroll
      for (int i = 0; i < 4; ++i)
        af[i] = *(const short8*)&As[(wr * 64 + i * 16 + lrow) * BK + kk * 32 + lk];
#pragma unroll
      for (int j = 0; j < 4; ++j)
        bf[j] = *(const short8*)&Bs[(wc * 64 + j * 16 + lrow) * BK + kk * 32 + lk];
#pragma unroll
      for (int i = 0; i < 4; ++i)
#pragma unroll
        for (int j = 0; j < 4; ++j)
          acc[i][j] = __builtin_amdgcn_mfma_f32_16x16x32_bf16(
              af[i], bf[j], acc[i][j], 0, 0, 0);
    }
    __syncthreads();
  }

  const int crow0 = bm + wr * 64 + (lane >> 4) * 4;
  const int ccol0 = bn + wc * 64 + (lane & 15);
#pragma unroll
  for (int j = 0; j < 4; ++j) {
    const float bv = bias[ccol0 + j * 16];
#pragma unroll
    for (int i = 0; i < 4; ++i) {
#pragma unroll
      for (int r = 0; r < 4; ++r) {
        C[(size_t)(crow0 + i * 16 + r) * N + ccol0 + j * 16] = acc[i][j][r] + bv;
      }
    }
  }
}

// ---------------------------------------------------------------------------
// Last-resort fallback: naive fused dequant GEMM.
// ---------------------------------------------------------------------------
__global__ __launch_bounds__(256) void naive_kernel(
    const float* __restrict__ x, const float* __restrict__ scales,
    const float* __restrict__ bias, const int* __restrict__ qw,
    const int* __restrict__ qz, float* __restrict__ out,
    int M, int K, int N) {
  long idx = (long)blockIdx.x * blockDim.x + threadIdx.x;
  if (idx >= (long)M * N) return;
  const int n = (int)(idx % N);
  const int m = (int)(idx / N);
  float acc = 0.f;
  for (int g = 0; g < K / 128; ++g) {
    const float sc = scales[(size_t)g * N + n];
    const float zp =
        (float)(((qz[(size_t)g * (N >> 3) + (n >> 3)] >> ((n & 7) * 4)) & 15) + 1);
    const float zs = zp * sc;
    for (int kw = 0; kw < 16; ++kw) {
      const int w = qw[(size_t)(g * 16 + kw) * N + n];
      const float* xp = &x[(size_t)m * K + g * 128 + kw * 8];
#pragma unroll
      for (int e = 0; e < 8; ++e)
        acc += xp[e] * ((float)((w >> (4 * e)) & 15) * sc - zs);
    }
  }
  out[idx] = acc + bias[n];
}

// ---------------------------------------------------------------------------
extern "C" void kernel_launch(void* const* d_in, const int* in_sizes, int n_in,
                              void* d_out, int out_size, void* d_ws,
                              size_t ws_size, hipStream_t stream) {
  const float* x = (const float*)d_in[0];
  const float* scales = (const float*)d_in[1];
  const float* bias = (const float*)d_in[2];
  const int* qweight = (const int*)d_in[3];
  const int* qzeros = (const int*)d_in[4];
  float* out = (float*)d_out;

  const int out_f = in_sizes[2];            // 12288
  const int kwords = in_sizes[3] / out_f;   // 512
  const int in_f = kwords * 8;              // 4096
  const int tokens = in_sizes[0] / in_f;    // 8192
  const int M = tokens, K = in_f, N = out_f;

  const size_t wt_bytes = (size_t)K * N * sizeof(short);
  const size_t xb_bytes = (size_t)M * K * sizeof(short);

  const bool div128 = (M % BM == 0) && (N % BN == 0) && (K % BK == 0) &&
                      (K % 128 == 0) && (N % 64 == 0);
  const bool div256 = (M % GBM == 0) && (N % GBN == 0) && (K % 128 == 0) &&
                      (N % 64 == 0);

  if (div128 && ws_size >= wt_bytes + xb_bytes) {
    short* Wt = (short*)d_ws;
    short* xb = (short*)((char*)d_ws + wt_bytes);
    dequant_kernel<<<dim3(N / 64, K / 64), 256, 0, stream>>>(
        qweight, qzeros, scales, Wt, K, N);
    const long n8 = (long)M * K / 8;
    cvt_kernel<<<(int)((n8 + 255) / 256), 256, 0, stream>>>(x, xb, n8);
    if (div256) {
      gemm256_kernel<<<(M / GBM) * (N / GBN), 512, 0, stream>>>(
          xb, Wt, bias, out, M, N, K);
    } else {
      gemm_bias_kernel<true><<<dim3(N / BN, M / BM), 256, 0, stream>>>(
          xb, Wt, bias, out, M, N, K);
    }
  } else if (div128 && ws_size >= wt_bytes) {
    short* Wt = (short*)d_ws;
    dequant_kernel<<<dim3(N / 64, K / 64), 256, 0, stream>>>(
        qweight, qzeros, scales, Wt, K, N);
    gemm_bias_kernel<false><<<dim3(N / BN, M / BM), 256, 0, stream>>>(
        x, Wt, bias, out, M, N, K);
  } else {
    const long total = (long)M * N;
    naive_kernel<<<(int)((total + 255) / 256), 256, 0, stream>>>(
        x, scales, bias, qweight, qzeros, out, M, K, N);
  }
}